// Round 3
// baseline (217.128 us; speedup 1.0000x reference)
//
#include <hip/hip_runtime.h>

// DynamicMemoryCell: B=8, N=2048, IN=256, MEM=256, CTX=128
// out0 = new_memory [8,2048,256] f32 ; out1 = attention_probs [8,2048,2048] f32
// Wv/value/context are dead in the reference -> skipped.

typedef _Float16 half8 __attribute__((ext_vector_type(8)));
typedef float floatx4 __attribute__((ext_vector_type(4)));

#define MFMA16(a, b, c) __builtin_amdgcn_mfma_f32_16x16x32_f16((a), (b), (c), 0, 0, 0)

// ws layout (units: _Float16)
#define OFF_WQH 0
#define OFF_WQL 32768
#define OFF_WKH 65536
#define OFF_WKL 98304
#define OFF_WUH 131072
#define OFF_WRH 262144
#define OFF_WCH 393216
#define OFF_Q   524288
#define OFF_K   2621440
// total = 4718592 halves = 9,437,184 bytes

__device__ __forceinline__ void gload16(const void* g, void* l) {
  __builtin_amdgcn_global_load_lds((const __attribute__((address_space(1))) unsigned int*)g,
                                   (__attribute__((address_space(3))) unsigned int*)l, 16, 0, 0);
}

// Stage a 16 KB weight tile (32 cols x 256 K fp16) L2->LDS, source pre-swizzled so that
// reading LDS at swz(o) returns global[o].  swz(o) = o ^ (((o>>9)&7)<<4)  (involution).
// gtile = W_base_bytes + np*32*1024 + kh*512   (row stride in global = 1024 B)
__device__ __forceinline__ void stage16k(const char* gtile, char* ldsbuf, int w, int lane) {
#pragma unroll
  for (int r = 0; r < 4; ++r) {
    int o = w * 1024 + r * 4096 + lane * 16;
    int row = o >> 9;
    int src = row * 1024 + ((o & 511) ^ ((row & 7) << 4));
    gload16(gtile + src, ldsbuf + w * 1024 + r * 4096);
  }
}

// Read one B-fragment (16B/lane) from a staged tile. rowidx = in-tile col index (0..31).
__device__ __forceinline__ half8 rdfrag(const char* buf, int rowidx, int ksl, int lg, int lr) {
  int off = (rowidx * 512 + ksl * 64 + lg * 16) ^ ((lr & 7) << 4);
  return *(const half8*)(buf + off);
}

// ---------------------------------------------------------------- K0: weights fp32 -> fp16 (hi/lo split for Wq/Wk)
__global__ __launch_bounds__(256) void k0_convert(
    const float* __restrict__ Wq, const float* __restrict__ Wk,
    const float* __restrict__ Wu, const float* __restrict__ Wr,
    const float* __restrict__ Wc, _Float16* __restrict__ ws)
{
  int i = blockIdx.x * 256 + threadIdx.x;
  if (i < 32768) {
    float w = Wq[i];
    _Float16 h = (_Float16)w;
    ws[OFF_WQH + i] = h;
    ws[OFF_WQL + i] = (_Float16)(w - (float)h);
  } else if (i < 65536) {
    int j = i - 32768;
    float w = Wk[j];
    _Float16 h = (_Float16)w;
    ws[OFF_WKH + j] = h;
    ws[OFF_WKL + j] = (_Float16)(w - (float)h);
  } else {
    int j = i - 65536;
    if (j < 131072)      ws[OFF_WUH + j]            = (_Float16)Wu[j];
    else if (j < 262144) ws[OFF_WRH + (j - 131072)] = (_Float16)Wr[j - 131072];
    else                 ws[OFF_WCH + (j - 262144)] = (_Float16)Wc[j - 262144];
  }
}

// ---------------------------------------------------------------- K1: Q/K projection, split-fp16 MFMA (3 products)
__global__ __launch_bounds__(256) void k1_proj(
    const float* __restrict__ input, const float* __restrict__ prev,
    const float* __restrict__ bq, const float* __restrict__ bk,
    _Float16* __restrict__ ws)
{
  const int which = blockIdx.y;
  const float* x = which ? prev : input;
  const _Float16* Wh = ws + (which ? OFF_WKH : OFF_WQH);
  const _Float16* Wl = ws + (which ? OFF_WKL : OFF_WQL);
  const float* bias = which ? bk : bq;
  _Float16* out = ws + (which ? OFF_K : OFF_Q);

  const int tid = threadIdx.x;
  const int wave = tid >> 6, l = tid & 63;
  const int lr = l & 15, lg = l >> 4;
  const int row0 = blockIdx.x * 64 + wave * 16;

  const float* xrow = x + (size_t)(row0 + lr) * 256 + lg * 8;
  half8 xh[8], xl[8];
#pragma unroll
  for (int ks = 0; ks < 8; ++ks) {
    floatx4 a = *(const floatx4*)(xrow + ks * 32);
    floatx4 b = *(const floatx4*)(xrow + ks * 32 + 4);
    half8 h, lo;
#pragma unroll
    for (int j = 0; j < 4; ++j) {
      h[j]     = (_Float16)a[j]; lo[j]     = (_Float16)(a[j] - (float)h[j]);
      h[4 + j] = (_Float16)b[j]; lo[4 + j] = (_Float16)(b[j] - (float)h[4 + j]);
    }
    xh[ks] = h; xl[ks] = lo;
  }

#pragma unroll 1
  for (int nt = 0; nt < 8; ++nt) {
    const _Float16* wph = Wh + (size_t)(nt * 16 + lr) * 256 + lg * 8;
    const _Float16* wpl = Wl + (size_t)(nt * 16 + lr) * 256 + lg * 8;
    floatx4 acc = {0.f, 0.f, 0.f, 0.f};
#pragma unroll
    for (int ks = 0; ks < 8; ++ks) {
      half8 wh = *(const half8*)(wph + ks * 32);
      half8 wl = *(const half8*)(wpl + ks * 32);
      acc = MFMA16(xh[ks], wh, acc);
      acc = MFMA16(xl[ks], wh, acc);
      acc = MFMA16(xh[ks], wl, acc);
    }
    float bv = bias[nt * 16 + lr];
#pragma unroll
    for (int j = 0; j < 4; ++j)
      out[(size_t)(row0 + lg * 4 + j) * 128 + nt * 16 + lr] = (_Float16)(acc[j] + bv);
  }
}

// ---------------------------------------------------------------- K2: fused GRU gates -> new_memory
// 512 blocks x 256 thr. 32 rows/block. 4 waves = 2 row-tiles x 2 col-halves.
// Weights staged L2->LDS async (global_load_lds, 16 KB tiles, double-buffered).
// LDS: wbuf 2x16KB | t 16KB | m 16KB = 64 KB -> 2 blocks/CU.
__global__ __launch_bounds__(256) void k2_gates(
    const float* __restrict__ input, const float* __restrict__ prev,
    const float* __restrict__ bu, const float* __restrict__ br,
    const float* __restrict__ bc, const _Float16* __restrict__ ws,
    float* __restrict__ out0)
{
  __shared__ char smem[65536];
  char* tld = smem + 32768;   // t = sigma(r)*m, fp16 [32][256] swizzled
  char* mld = smem + 49152;   // m (prev) fp16 [32][256] swizzled

  const int tid = threadIdx.x;
  const int w = tid >> 6, lane = tid & 63;
  const int lr = lane & 15, lg = lane >> 4;
  const int tr = w & 1, tc = w >> 1;        // row-tile, col-half
  const int row0 = blockIdx.x * 32;
  const int myrow = row0 + tr * 16 + lr;

  // A-frags (combined = [input | prev], K=512) for this wave's 16 rows
  half8 ah[16];
  {
    const float* xr = input + (size_t)myrow * 256 + lg * 8;
    const float* mr = prev  + (size_t)myrow * 256 + lg * 8;
#pragma unroll
    for (int ks = 0; ks < 8; ++ks) {
      floatx4 a = *(const floatx4*)(xr + ks * 32);
      floatx4 b = *(const floatx4*)(xr + ks * 32 + 4);
      half8 h;
#pragma unroll
      for (int j = 0; j < 4; ++j) { h[j] = (_Float16)a[j]; h[4 + j] = (_Float16)b[j]; }
      ah[ks] = h;
    }
#pragma unroll
    for (int ks = 0; ks < 8; ++ks) {
      floatx4 a = *(const floatx4*)(mr + ks * 32);
      floatx4 b = *(const floatx4*)(mr + ks * 32 + 4);
      half8 h;
#pragma unroll
      for (int j = 0; j < 4; ++j) { h[j] = (_Float16)a[j]; h[4 + j] = (_Float16)b[j]; }
      ah[8 + ks] = h;
    }
  }

  const char* Wr_b = (const char*)(ws + OFF_WRH);
  const char* Wu_b = (const char*)(ws + OFF_WUH);
  const char* Wc_b = (const char*)(ws + OFF_WCH);
  const int rowidx = tc * 16 + lr;   // in-staged-tile col index

  // ================= pass 1: reset gate -> t, m in LDS =================
  stage16k(Wr_b, smem, w, lane);                       // s=0 tile (np0,kh0)
  __syncthreads();
  floatx4 aR = {0.f, 0.f, 0.f, 0.f};
#pragma unroll 1
  for (int s = 0; s < 16; ++s) {
    const int np = s >> 1, kh = s & 1;
    if (s + 1 < 16) {
      const int np1 = (s + 1) >> 1, kh1 = (s + 1) & 1;
      stage16k(Wr_b + np1 * 32768 + kh1 * 512, ((s + 1) & 1) ? smem + 16384 : smem, w, lane);
    }
    const char* buf = (s & 1) ? smem + 16384 : smem;
    if (kh == 0) { floatx4 z = {0.f,0.f,0.f,0.f}; aR = z; }
#pragma unroll
    for (int ksl = 0; ksl < 8; ++ksl) {
      half8 wf = rdfrag(buf, rowidx, ksl, lg, lr);
      aR = MFMA16(ah[kh * 8 + ksl], wf, aR);
    }
    if (kh == 1) {
      const int colL = np * 32 + tc * 16 + lr;
      const float bv = br[colL];
#pragma unroll
      for (int j = 0; j < 4; ++j) {
        const int rrow = tr * 16 + lg * 4 + j;
        float rg = 1.f / (1.f + __expf(-(aR[j] + bv)));
        float mv = prev[(size_t)(row0 + rrow) * 256 + colL];
        int toff = (rrow * 512 + colL * 2) ^ ((rrow & 7) << 4);
        *(_Float16*)(tld + toff) = (_Float16)(rg * mv);
        *(_Float16*)(mld + toff) = (_Float16)mv;
      }
    }
    __syncthreads();
  }

  // ================= pass 2: update gate + candidate -> out0 =================
  // step s: np = s>>2 (32-col group), kh = (s>>1)&1, mat = s&1 (0=U, 1=C)
  stage16k(Wu_b, smem, w, lane);                       // s=0 tile (np0,kh0,U)
  __syncthreads();
  floatx4 aU = {0.f,0.f,0.f,0.f}, aC = {0.f,0.f,0.f,0.f};
#pragma unroll 1
  for (int s = 0; s < 32; ++s) {
    const int np = s >> 2, kh = (s >> 1) & 1, mat = s & 1;
    if (s + 1 < 32) {
      const int s1 = s + 1;
      const int np1 = s1 >> 2, kh1 = (s1 >> 1) & 1, mat1 = s1 & 1;
      const char* gsrc = (mat1 ? Wc_b : Wu_b) + np1 * 32768 + kh1 * 512;
      stage16k(gsrc, (s1 & 1) ? smem + 16384 : smem, w, lane);
    }
    const char* buf = (s & 1) ? smem + 16384 : smem;
    if ((s & 3) == 0) { floatx4 z = {0.f,0.f,0.f,0.f}; aU = z; aC = z; }
    if (mat == 0) {
#pragma unroll
      for (int ksl = 0; ksl < 8; ++ksl) {
        half8 wf = rdfrag(buf, rowidx, ksl, lg, lr);
        aU = MFMA16(ah[kh * 8 + ksl], wf, aU);
      }
    } else {
      if (kh == 0) {
#pragma unroll
        for (int ksl = 0; ksl < 8; ++ksl) {
          half8 wf = rdfrag(buf, rowidx, ksl, lg, lr);
          aC = MFMA16(ah[ksl], wf, aC);
        }
      } else {
#pragma unroll
        for (int ksl = 0; ksl < 8; ++ksl) {
          half8 wf = rdfrag(buf, rowidx, ksl, lg, lr);
          int toff2 = ((tr * 16 + lr) * 512 + ksl * 64 + lg * 16) ^ ((lr & 7) << 4);
          half8 af = *(const half8*)(tld + toff2);
          aC = MFMA16(af, wf, aC);
        }
      }
    }
    if ((s & 3) == 3) {
      const int colL = np * 32 + tc * 16 + lr;
      const float bvu = bu[colL], bvc = bc[colL];
#pragma unroll
      for (int j = 0; j < 4; ++j) {
        const int rrow = tr * 16 + lg * 4 + j;
        float ug = 1.f / (1.f + __expf(-(aU[j] + bvu)));
        float e2 = __expf(2.f * (aC[j] + bvc));
        float cg = (e2 - 1.f) / (e2 + 1.f);
        int toff = (rrow * 512 + colL * 2) ^ ((rrow & 7) << 4);
        float mv = (float)*(const _Float16*)(mld + toff);
        out0[(size_t)(row0 + rrow) * 256 + colL] = (1.f - ug) * mv + ug * cg;
      }
    }
    __syncthreads();
  }
}

// ---------------------------------------------------------------- K3: attention scores + softmax (2-pass recompute)
// grid (64, 8) x 512 thr; block = 32 q-rows; 8 waves split keys (256 each).
__global__ __launch_bounds__(512) void k3_attn(
    const _Float16* __restrict__ ws, float* __restrict__ out1)
{
  __shared__ float sums[8][32];
  const int b = blockIdx.y;
  const int tid = threadIdx.x;
  const int w = tid >> 6, l = tid & 63;
  const int lr = l & 15, lg = l >> 4;
  const int q0 = blockIdx.x * 32;

  const _Float16* Q  = ws + OFF_Q + ((size_t)b * 2048 + q0) * 128;
  const _Float16* Kp = ws + OFF_K + (size_t)b * 2048 * 128 + (size_t)w * 256 * 128;

  half8 qf[2][4];
#pragma unroll
  for (int qt = 0; qt < 2; ++qt)
#pragma unroll
    for (int ks = 0; ks < 4; ++ks)
      qf[qt][ks] = *(const half8*)(Q + (size_t)(qt * 16 + lr) * 128 + ks * 32 + lg * 8);

  float se0[4] = {0.f,0.f,0.f,0.f}, se1[4] = {0.f,0.f,0.f,0.f};
#pragma unroll 1
  for (int kt = 0; kt < 16; ++kt) {
    const _Float16* kp = Kp + (size_t)(kt * 16 + lr) * 128 + lg * 8;
    half8 kf[4];
#pragma unroll
    for (int ks = 0; ks < 4; ++ks) kf[ks] = *(const half8*)(kp + ks * 32);
    floatx4 a00 = {0.f,0.f,0.f,0.f}, a10 = {0.f,0.f,0.f,0.f};
#pragma unroll
    for (int ks = 0; ks < 4; ++ks) {
      a00 = MFMA16(qf[0][ks], kf[ks], a00);
      a10 = MFMA16(qf[1][ks], kf[ks], a10);
    }
#pragma unroll
    for (int j = 0; j < 4; ++j) { se0[j] += __expf(a00[j]); se1[j] += __expf(a10[j]); }
  }
#pragma unroll
  for (int m = 1; m < 16; m <<= 1) {
#pragma unroll
    for (int j = 0; j < 4; ++j) { se0[j] += __shfl_xor(se0[j], m); se1[j] += __shfl_xor(se1[j], m); }
  }
  if (lr == 0) {
#pragma unroll
    for (int j = 0; j < 4; ++j) { sums[w][lg * 4 + j] = se0[j]; sums[w][16 + lg * 4 + j] = se1[j]; }
  }
  __syncthreads();
  float inv0[4], inv1[4];
#pragma unroll
  for (int j = 0; j < 4; ++j) {
    int r0 = lg * 4 + j, r1 = 16 + lg * 4 + j;
    float s0 = 0.f, s1 = 0.f;
#pragma unroll
    for (int ww = 0; ww < 8; ++ww) { s0 += sums[ww][r0]; s1 += sums[ww][r1]; }
    inv0[j] = 1.f / s0; inv1[j] = 1.f / s1;
  }

  float* orow = out1 + ((size_t)b * 2048 + q0) * 2048 + w * 256;
#pragma unroll 1
  for (int kt = 0; kt < 16; ++kt) {
    const _Float16* kp = Kp + (size_t)(kt * 16 + lr) * 128 + lg * 8;
    half8 kf[4];
#pragma unroll
    for (int ks = 0; ks < 4; ++ks) kf[ks] = *(const half8*)(kp + ks * 32);
    floatx4 a00 = {0.f,0.f,0.f,0.f}, a10 = {0.f,0.f,0.f,0.f};
#pragma unroll
    for (int ks = 0; ks < 4; ++ks) {
      a00 = MFMA16(qf[0][ks], kf[ks], a00);
      a10 = MFMA16(qf[1][ks], kf[ks], a10);
    }
    float* o0 = orow + (size_t)(lg * 4) * 2048 + kt * 16 + lr;
    float* o1 = o0 + (size_t)16 * 2048;
#pragma unroll
    for (int j = 0; j < 4; ++j) {
      o0[(size_t)j * 2048] = __expf(a00[j]) * inv0[j];
      o1[(size_t)j * 2048] = __expf(a10[j]) * inv1[j];
    }
  }
}

// ----------------------------------------------------------------
extern "C" void kernel_launch(void* const* d_in, const int* in_sizes, int n_in,
                              void* d_out, int out_size, void* d_ws, size_t ws_size,
                              hipStream_t stream)
{
  const float* input = (const float*)d_in[0];
  const float* prev  = (const float*)d_in[1];
  const float* Wq = (const float*)d_in[2];
  const float* bq = (const float*)d_in[3];
  const float* Wk = (const float*)d_in[4];
  const float* bk = (const float*)d_in[5];
  const float* Wu = (const float*)d_in[8];
  const float* bu = (const float*)d_in[9];
  const float* Wr = (const float*)d_in[10];
  const float* br = (const float*)d_in[11];
  const float* Wc = (const float*)d_in[12];
  const float* bc = (const float*)d_in[13];

  float* out0 = (float*)d_out;                       // new_memory [8,2048,256]
  float* out1 = out0 + (size_t)8 * 2048 * 256;       // attention_probs [8,2048,2048]
  _Float16* ws = (_Float16*)d_ws;                    // needs 9,437,184 bytes

  hipLaunchKernelGGL(k0_convert, dim3(1792), dim3(256), 0, stream, Wq, Wk, Wu, Wr, Wc, ws);
  hipLaunchKernelGGL(k1_proj,    dim3(256, 2), dim3(256), 0, stream, input, prev, bq, bk, ws);
  hipLaunchKernelGGL(k2_gates,   dim3(512), dim3(256), 0, stream, input, prev, bu, br, bc, ws, out0);
  hipLaunchKernelGGL(k3_attn,    dim3(64, 8), dim3(512), 0, stream, ws, out1);
}

// Round 4
// 170.189 us; speedup vs baseline: 1.2758x; 1.2758x over previous
//
#include <hip/hip_runtime.h>

// DynamicMemoryCell: B=8, N=2048, IN=256, MEM=256, CTX=128
// out0 = new_memory [8,2048,256] f32 ; out1 = attention_probs [8,2048,2048] f32
// Wv/value/context are dead in the reference -> skipped.
//
// Structure (R3): weights-in-registers, activations streamed through LDS.
//  k0: weights fp32->fp16 (hi/lo split for Wq/Wk)
//  k1: Q/K projection  (split-fp16, B hi/lo in regs, A hi/lo LDS chunks)
//  k2a: reset gate -> t = sigmoid(r)*m  (fp16, ws)     [needs ws >= 17.8 MB]
//  k2b: update+candidate+combine -> out0
//  k2_fallback: proven R1 kernel if ws too small
//  k3: attention scores + softmax, 2-pass recompute

typedef _Float16 half8 __attribute__((ext_vector_type(8)));
typedef float floatx4 __attribute__((ext_vector_type(4)));

#define MFMA16(a, b, c) __builtin_amdgcn_mfma_f32_16x16x32_f16((a), (b), (c), 0, 0, 0)

// ws layout (units: _Float16)
#define OFF_WQH 0
#define OFF_WQL 32768
#define OFF_WKH 65536
#define OFF_WKL 98304
#define OFF_WUH 131072
#define OFF_WRH 262144
#define OFF_WCH 393216
#define OFF_Q   524288
#define OFF_K   2621440
#define OFF_T   4718592
// end = 8912896 halves = 17,825,792 bytes (OFF_T region optional -> fallback)

// ---------------------------------------------------------------- K0
__global__ __launch_bounds__(256) void k0_convert(
    const float* __restrict__ Wq, const float* __restrict__ Wk,
    const float* __restrict__ Wu, const float* __restrict__ Wr,
    const float* __restrict__ Wc, _Float16* __restrict__ ws)
{
  int i = blockIdx.x * 256 + threadIdx.x;
  if (i < 32768) {
    float w = Wq[i];
    _Float16 h = (_Float16)w;
    ws[OFF_WQH + i] = h;
    ws[OFF_WQL + i] = (_Float16)(w - (float)h);
  } else if (i < 65536) {
    int j = i - 32768;
    float w = Wk[j];
    _Float16 h = (_Float16)w;
    ws[OFF_WKH + j] = h;
    ws[OFF_WKL + j] = (_Float16)(w - (float)h);
  } else {
    int j = i - 65536;
    if (j < 131072)      ws[OFF_WUH + j]            = (_Float16)Wu[j];
    else if (j < 262144) ws[OFF_WRH + (j - 131072)] = (_Float16)Wr[j - 131072];
    else                 ws[OFF_WCH + (j - 262144)] = (_Float16)Wc[j - 262144];
  }
}

// ---------------------------------------------------------------- K1: Q/K projection
// grid (64, 2, 2) x 256. Block: 256 rows x 64 cols; wave w -> 16 cols (B hi/lo in 64 VGPR).
// A (x) hi/lo staged per 32-row chunk into LDS (double-buffered, XOR-swizzled).
__global__ __launch_bounds__(256) void k1_proj(
    const float* __restrict__ input, const float* __restrict__ prev,
    const float* __restrict__ bq, const float* __restrict__ bk,
    _Float16* __restrict__ ws)
{
  __shared__ char smem[2 * 32768];   // chunk: 32 rows x [hi 512B | lo 512B]
  const int which = blockIdx.z;
  const float* x = which ? prev : input;
  const _Float16* WH = ws + (which ? OFF_WKH : OFF_WQH);
  const _Float16* WL = ws + (which ? OFF_WKL : OFF_WQL);
  const float* bias = which ? bk : bq;
  _Float16* out = ws + (which ? OFF_K : OFF_Q);

  const int tid = threadIdx.x, w = tid >> 6, l = tid & 63;
  const int lr = l & 15, lg = l >> 4;
  const int rows0 = blockIdx.x * 256;
  const int c = blockIdx.y * 64 + w * 16 + lr;

  half8 bh[8], bl[8];
#pragma unroll
  for (int ks = 0; ks < 8; ++ks) {
    bh[ks] = *(const half8*)(WH + (size_t)c * 256 + ks * 32 + lg * 8);
    bl[ks] = *(const half8*)(WL + (size_t)c * 256 + ks * 32 + lg * 8);
  }
  const float bv = bias[c];

  const int srow = tid >> 3, spart = tid & 7;   // staging: 32 rows x 8 parts (32 floats each)
  const int ssz = (srow & 7) << 4;
  floatx4 st[8];

#define K1_LOAD(ch) { const float* src = x + (size_t)(rows0 + (ch) * 32 + srow) * 256 + spart * 32; \
  _Pragma("unroll") for (int i = 0; i < 8; ++i) st[i] = *(const floatx4*)(src + i * 4); }
#define K1_WRITE(ch) { char* bufw = smem + ((ch) & 1) * 32768; \
  _Pragma("unroll") for (int i2 = 0; i2 < 4; ++i2) { \
    floatx4 a = st[2 * i2], b = st[2 * i2 + 1]; half8 h, lo; \
    _Pragma("unroll") for (int j = 0; j < 4; ++j) { \
      h[j] = (_Float16)a[j]; lo[j] = (_Float16)(a[j] - (float)h[j]); \
      h[4 + j] = (_Float16)b[j]; lo[4 + j] = (_Float16)(b[j] - (float)h[4 + j]); } \
    int o = (spart * 64 + i2 * 16) ^ ssz; \
    *(half8*)(bufw + srow * 1024 + o) = h; \
    *(half8*)(bufw + srow * 1024 + 512 + o) = lo; } }

  K1_LOAD(0); K1_WRITE(0);
  __syncthreads();
#pragma unroll 1
  for (int ch = 0; ch < 8; ++ch) {
    if (ch < 7) K1_LOAD(ch + 1);
    const char* buf = smem + (ch & 1) * 32768;
#pragma unroll
    for (int rt = 0; rt < 2; ++rt) {
      floatx4 acc = {0.f, 0.f, 0.f, 0.f};
      const int arow = rt * 16 + lr, base = arow * 1024, sz = (arow & 7) << 4;
#pragma unroll
      for (int ks = 0; ks < 8; ++ks) {
        int o = (ks * 64 + lg * 16) ^ sz;
        half8 ah = *(const half8*)(buf + base + o);
        half8 al = *(const half8*)(buf + base + 512 + o);
        acc = MFMA16(ah, bh[ks], acc);
        acc = MFMA16(al, bh[ks], acc);
        acc = MFMA16(ah, bl[ks], acc);
      }
#pragma unroll
      for (int j = 0; j < 4; ++j)
        out[(size_t)(rows0 + ch * 32 + rt * 16 + lg * 4 + j) * 128 + c] = (_Float16)(acc[j] + bv);
    }
    if (ch < 7) K1_WRITE(ch + 1);
    __syncthreads();
  }
}

// ---------------------------------------------------------------- K2a: reset gate -> t fp16 in ws
// grid (64, 4) x 256. Block: 256 rows x 64 cols; wave -> 16 cols, Wr frags in 64 VGPR.
// A = [input|prev] fp16 staged per 32-row chunk (32 KB, double-buffered).
__global__ __launch_bounds__(256) void k2a_reset(
    const float* __restrict__ input, const float* __restrict__ prev,
    const float* __restrict__ br, const _Float16* __restrict__ ws,
    _Float16* __restrict__ tout)
{
  __shared__ char smem[2 * 32768];   // chunk: 32 rows x [input 512B | prev 512B]
  const int tid = threadIdx.x, w = tid >> 6, l = tid & 63;
  const int lr = l & 15, lg = l >> 4;
  const int rows0 = blockIdx.x * 256;
  const int c = blockIdx.y * 64 + w * 16 + lr;

  half8 bw[16];
#pragma unroll
  for (int ks = 0; ks < 16; ++ks)
    bw[ks] = *(const half8*)(ws + OFF_WRH + (size_t)c * 512 + ks * 32 + lg * 8);
  const float bv = br[c];

  const int srow = tid >> 3, spart = tid & 7;   // 32 rows x 8 parts (64 floats each)
  const int ssz = (srow & 7) << 4;
  floatx4 st[16];

#define K2A_LOAD(ch) { const float* src = (spart < 4) \
    ? input + (size_t)(rows0 + (ch) * 32 + srow) * 256 + spart * 64 \
    : prev  + (size_t)(rows0 + (ch) * 32 + srow) * 256 + (spart - 4) * 64; \
  _Pragma("unroll") for (int i = 0; i < 16; ++i) st[i] = *(const floatx4*)(src + i * 4); }
#define K2A_WRITE(ch) { char* bufw = smem + ((ch) & 1) * 32768; \
  _Pragma("unroll") for (int i2 = 0; i2 < 8; ++i2) { \
    floatx4 a = st[2 * i2], b = st[2 * i2 + 1]; half8 h; \
    _Pragma("unroll") for (int j = 0; j < 4; ++j) { h[j] = (_Float16)a[j]; h[4 + j] = (_Float16)b[j]; } \
    *(half8*)(bufw + srow * 1024 + ((spart * 128 + i2 * 16) ^ ssz)) = h; } }

  K2A_LOAD(0); K2A_WRITE(0);
  __syncthreads();
#pragma unroll 1
  for (int ch = 0; ch < 8; ++ch) {
    if (ch < 7) K2A_LOAD(ch + 1);
    const char* buf = smem + (ch & 1) * 32768;
#pragma unroll
    for (int rt = 0; rt < 2; ++rt) {
      floatx4 acc = {0.f, 0.f, 0.f, 0.f};
      const int arow = rt * 16 + lr, base = arow * 1024, sz = (arow & 7) << 4;
#pragma unroll
      for (int ks = 0; ks < 16; ++ks) {
        half8 a = *(const half8*)(buf + base + ((ks * 64 + lg * 16) ^ sz));
        acc = MFMA16(a, bw[ks], acc);
      }
#pragma unroll
      for (int j = 0; j < 4; ++j) {
        const int crow = rt * 16 + lg * 4 + j;
        float m = (float)*(const _Float16*)(buf + crow * 1024 + 512 + ((c * 2) ^ ((crow & 7) << 4)));
        float rg = 1.f / (1.f + __expf(-(acc[j] + bv)));
        tout[(size_t)(rows0 + ch * 32 + crow) * 256 + c] = (_Float16)(rg * m);
      }
    }
    if (ch < 7) K2A_WRITE(ch + 1);
    __syncthreads();
  }
}

// ---------------------------------------------------------------- K2b: update + candidate + combine -> out0
// grid (64, 4) x 256. Wave -> 16 cols; Wu + Wc frags in 128 VGPR.
// A chunk: 32 rows x [input 512B | prev 512B | t 512B] = 48 KB, double-buffered.
__global__ __launch_bounds__(256) void k2b_update(
    const float* __restrict__ input, const float* __restrict__ prev,
    const float* __restrict__ bu, const float* __restrict__ bc,
    const _Float16* __restrict__ ws, const _Float16* __restrict__ tin,
    float* __restrict__ out0)
{
  __shared__ char smem[2 * 49152];
  const int tid = threadIdx.x, w = tid >> 6, l = tid & 63;
  const int lr = l & 15, lg = l >> 4;
  const int rows0 = blockIdx.x * 256;
  const int c = blockIdx.y * 64 + w * 16 + lr;

  half8 bU[16], bC[16];
#pragma unroll
  for (int ks = 0; ks < 16; ++ks) {
    bU[ks] = *(const half8*)(ws + OFF_WUH + (size_t)c * 512 + ks * 32 + lg * 8);
    bC[ks] = *(const half8*)(ws + OFF_WCH + (size_t)c * 512 + ks * 32 + lg * 8);
  }
  const float bvu = bu[c], bvc = bc[c];

  const int srow = tid >> 3, spart = tid & 7;   // 32 rows x 8 parts (32 f32 in + 32 f32 prev + 32 h t)
  const int ssz = (srow & 7) << 4;
  floatx4 stI[8], stP[8];
  half8 stT[4];

#define K2B_LOAD(ch) { \
  const float* si = input + (size_t)(rows0 + (ch) * 32 + srow) * 256 + spart * 32; \
  const float* sp = prev  + (size_t)(rows0 + (ch) * 32 + srow) * 256 + spart * 32; \
  const _Float16* stt = tin + (size_t)(rows0 + (ch) * 32 + srow) * 256 + spart * 32; \
  _Pragma("unroll") for (int i = 0; i < 8; ++i) { stI[i] = *(const floatx4*)(si + i * 4); \
                                                  stP[i] = *(const floatx4*)(sp + i * 4); } \
  _Pragma("unroll") for (int i = 0; i < 4; ++i) stT[i] = *(const half8*)(stt + i * 8); }
#define K2B_WRITE(ch) { char* bufw = smem + ((ch) & 1) * 49152; \
  _Pragma("unroll") for (int i2 = 0; i2 < 4; ++i2) { \
    floatx4 a = stI[2 * i2], b = stI[2 * i2 + 1], p = stP[2 * i2], q = stP[2 * i2 + 1]; \
    half8 h, hp; \
    _Pragma("unroll") for (int j = 0; j < 4; ++j) { h[j] = (_Float16)a[j]; h[4 + j] = (_Float16)b[j]; \
                                                    hp[j] = (_Float16)p[j]; hp[4 + j] = (_Float16)q[j]; } \
    int o = (spart * 64 + i2 * 16) ^ ssz; \
    *(half8*)(bufw + srow * 1536 + o) = h; \
    *(half8*)(bufw + srow * 1536 + 512 + o) = hp; \
    *(half8*)(bufw + srow * 1536 + 1024 + o) = stT[i2]; } }

  K2B_LOAD(0); K2B_WRITE(0);
  __syncthreads();
#pragma unroll 1
  for (int ch = 0; ch < 8; ++ch) {
    if (ch < 7) K2B_LOAD(ch + 1);
    const char* buf = smem + (ch & 1) * 49152;
#pragma unroll
    for (int rt = 0; rt < 2; ++rt) {
      floatx4 aU = {0.f, 0.f, 0.f, 0.f}, aC = {0.f, 0.f, 0.f, 0.f};
      const int arow = rt * 16 + lr, base = arow * 1536, sz = (arow & 7) << 4;
#pragma unroll
      for (int ks = 0; ks < 8; ++ks) {
        int o = (ks * 64 + lg * 16) ^ sz;
        half8 ai = *(const half8*)(buf + base + o);
        aU = MFMA16(ai, bU[ks], aU);
        aC = MFMA16(ai, bC[ks], aC);
      }
#pragma unroll
      for (int ks = 8; ks < 16; ++ks) {
        int o = ((ks - 8) * 64 + lg * 16) ^ sz;
        half8 ap = *(const half8*)(buf + base + 512 + o);
        aU = MFMA16(ap, bU[ks], aU);
        half8 at = *(const half8*)(buf + base + 1024 + o);
        aC = MFMA16(at, bC[ks], aC);
      }
#pragma unroll
      for (int j = 0; j < 4; ++j) {
        const int crow = rt * 16 + lg * 4 + j;
        float m = (float)*(const _Float16*)(buf + crow * 1536 + 512 + ((c * 2) ^ ((crow & 7) << 4)));
        float u = 1.f / (1.f + __expf(-(aU[j] + bvu)));
        float e2 = __expf(2.f * (aC[j] + bvc));
        float cg = (e2 - 1.f) / (e2 + 1.f);
        out0[(size_t)(rows0 + ch * 32 + crow) * 256 + c] = (1.f - u) * m + u * cg;
      }
    }
    if (ch < 7) K2B_WRITE(ch + 1);
    __syncthreads();
  }
}

// ---------------------------------------------------------------- K2 fallback (proven R1 kernel, used if ws too small)
__global__ __launch_bounds__(256) void k2_fallback(
    const float* __restrict__ input, const float* __restrict__ prev,
    const float* __restrict__ bu, const float* __restrict__ br,
    const float* __restrict__ bc, const _Float16* __restrict__ ws,
    float* __restrict__ out0)
{
  __shared__ char tlds[32 * 256 * 2];
  const int tid = threadIdx.x;
  const int w = tid >> 6, l = tid & 63;
  const int lr = l & 15, lg = l >> 4;
  const int row0 = blockIdx.x * 32;

  half8 ah[2][16];
#pragma unroll
  for (int mt = 0; mt < 2; ++mt) {
    const float* xr = input + (size_t)(row0 + mt * 16 + lr) * 256 + lg * 8;
    const float* mr = prev  + (size_t)(row0 + mt * 16 + lr) * 256 + lg * 8;
#pragma unroll
    for (int ks = 0; ks < 8; ++ks) {
      floatx4 a = *(const floatx4*)(xr + ks * 32);
      floatx4 b = *(const floatx4*)(xr + ks * 32 + 4);
      half8 h;
#pragma unroll
      for (int j = 0; j < 4; ++j) { h[j] = (_Float16)a[j]; h[4 + j] = (_Float16)b[j]; }
      ah[mt][ks] = h;
    }
#pragma unroll
    for (int ks = 0; ks < 8; ++ks) {
      floatx4 a = *(const floatx4*)(mr + ks * 32);
      floatx4 b = *(const floatx4*)(mr + ks * 32 + 4);
      half8 h;
#pragma unroll
      for (int j = 0; j < 4; ++j) { h[j] = (_Float16)a[j]; h[4 + j] = (_Float16)b[j]; }
      ah[mt][8 + ks] = h;
    }
  }
#pragma unroll 1
  for (int i = 0; i < 4; ++i) {
    const int nt = w * 4 + i;
    floatx4 acc0 = {0.f,0.f,0.f,0.f}, acc1 = {0.f,0.f,0.f,0.f};
    const _Float16* wp = ws + OFF_WRH + (size_t)(nt * 16 + lr) * 512 + lg * 8;
#pragma unroll
    for (int ks = 0; ks < 16; ++ks) {
      half8 wv = *(const half8*)(wp + ks * 32);
      acc0 = MFMA16(ah[0][ks], wv, acc0);
      acc1 = MFMA16(ah[1][ks], wv, acc1);
    }
    float bv = br[nt * 16 + lr];
    int col = nt * 16 + lr;
#pragma unroll
    for (int mt = 0; mt < 2; ++mt) {
      floatx4 acc = mt ? acc1 : acc0;
#pragma unroll
      for (int j = 0; j < 4; ++j) {
        int row = mt * 16 + lg * 4 + j;
        float rg = 1.f / (1.f + __expf(-(acc[j] + bv)));
        float mv = prev[(size_t)(row0 + row) * 256 + col];
        int byteoff = ((row * 256 + col) * 2) ^ ((row & 7) << 4);
        *(_Float16*)(tlds + byteoff) = (_Float16)(rg * mv);
      }
    }
  }
  __syncthreads();
#pragma unroll 1
  for (int i = 0; i < 4; ++i) {
    const int nt = w * 4 + i;
    floatx4 aU0 = {0.f,0.f,0.f,0.f}, aU1 = {0.f,0.f,0.f,0.f};
    floatx4 aC0 = {0.f,0.f,0.f,0.f}, aC1 = {0.f,0.f,0.f,0.f};
    const _Float16* wu = ws + OFF_WUH + (size_t)(nt * 16 + lr) * 512 + lg * 8;
    const _Float16* wc = ws + OFF_WCH + (size_t)(nt * 16 + lr) * 512 + lg * 8;
#pragma unroll
    for (int ks = 0; ks < 16; ++ks) {
      half8 wuf = *(const half8*)(wu + ks * 32);
      aU0 = MFMA16(ah[0][ks], wuf, aU0);
      aU1 = MFMA16(ah[1][ks], wuf, aU1);
      half8 wcf = *(const half8*)(wc + ks * 32);
      half8 a0, a1;
      if (ks < 8) { a0 = ah[0][ks]; a1 = ah[1][ks]; }
      else {
        int base0 = (lr * 512 + (ks - 8) * 64 + lg * 16) ^ ((lr & 7) << 4);
        int base1 = ((16 + lr) * 512 + (ks - 8) * 64 + lg * 16) ^ ((lr & 7) << 4);
        a0 = *(const half8*)(tlds + base0);
        a1 = *(const half8*)(tlds + base1);
      }
      aC0 = MFMA16(a0, wcf, aC0);
      aC1 = MFMA16(a1, wcf, aC1);
    }
    int col = nt * 16 + lr;
    float bvu = bu[col], bvc = bc[col];
#pragma unroll
    for (int mt = 0; mt < 2; ++mt) {
      floatx4 aU = mt ? aU1 : aU0;
      floatx4 aC = mt ? aC1 : aC0;
#pragma unroll
      for (int j = 0; j < 4; ++j) {
        int row = mt * 16 + lg * 4 + j;
        float ug = 1.f / (1.f + __expf(-(aU[j] + bvu)));
        float e2 = __expf(2.f * (aC[j] + bvc));
        float cg = (e2 - 1.f) / (e2 + 1.f);
        float mv = prev[(size_t)(row0 + row) * 256 + col];
        out0[(size_t)(row0 + row) * 256 + col] = (1.f - ug) * mv + ug * cg;
      }
    }
  }
}

// ---------------------------------------------------------------- K3: attention scores + softmax (2-pass recompute)
__global__ __launch_bounds__(512) void k3_attn(
    const _Float16* __restrict__ ws, float* __restrict__ out1)
{
  __shared__ float sums[8][32];
  const int b = blockIdx.y;
  const int tid = threadIdx.x;
  const int w = tid >> 6, l = tid & 63;
  const int lr = l & 15, lg = l >> 4;
  const int q0 = blockIdx.x * 32;

  const _Float16* Q  = ws + OFF_Q + ((size_t)b * 2048 + q0) * 128;
  const _Float16* Kp = ws + OFF_K + (size_t)b * 2048 * 128 + (size_t)w * 256 * 128;

  half8 qf[2][4];
#pragma unroll
  for (int qt = 0; qt < 2; ++qt)
#pragma unroll
    for (int ks = 0; ks < 4; ++ks)
      qf[qt][ks] = *(const half8*)(Q + (size_t)(qt * 16 + lr) * 128 + ks * 32 + lg * 8);

  float se0[4] = {0.f,0.f,0.f,0.f}, se1[4] = {0.f,0.f,0.f,0.f};
#pragma unroll 1
  for (int kt = 0; kt < 16; ++kt) {
    const _Float16* kp = Kp + (size_t)(kt * 16 + lr) * 128 + lg * 8;
    half8 kf[4];
#pragma unroll
    for (int ks = 0; ks < 4; ++ks) kf[ks] = *(const half8*)(kp + ks * 32);
    floatx4 a00 = {0.f,0.f,0.f,0.f}, a10 = {0.f,0.f,0.f,0.f};
#pragma unroll
    for (int ks = 0; ks < 4; ++ks) {
      a00 = MFMA16(qf[0][ks], kf[ks], a00);
      a10 = MFMA16(qf[1][ks], kf[ks], a10);
    }
#pragma unroll
    for (int j = 0; j < 4; ++j) { se0[j] += __expf(a00[j]); se1[j] += __expf(a10[j]); }
  }
#pragma unroll
  for (int m = 1; m < 16; m <<= 1) {
#pragma unroll
    for (int j = 0; j < 4; ++j) { se0[j] += __shfl_xor(se0[j], m); se1[j] += __shfl_xor(se1[j], m); }
  }
  if (lr == 0) {
#pragma unroll
    for (int j = 0; j < 4; ++j) { sums[w][lg * 4 + j] = se0[j]; sums[w][16 + lg * 4 + j] = se1[j]; }
  }
  __syncthreads();
  float inv0[4], inv1[4];
#pragma unroll
  for (int j = 0; j < 4; ++j) {
    int r0 = lg * 4 + j, r1 = 16 + lg * 4 + j;
    float s0 = 0.f, s1 = 0.f;
#pragma unroll
    for (int ww = 0; ww < 8; ++ww) { s0 += sums[ww][r0]; s1 += sums[ww][r1]; }
    inv0[j] = 1.f / s0; inv1[j] = 1.f / s1;
  }

  float* orow = out1 + ((size_t)b * 2048 + q0) * 2048 + w * 256;
#pragma unroll 1
  for (int kt = 0; kt < 16; ++kt) {
    const _Float16* kp = Kp + (size_t)(kt * 16 + lr) * 128 + lg * 8;
    half8 kf[4];
#pragma unroll
    for (int ks = 0; ks < 4; ++ks) kf[ks] = *(const half8*)(kp + ks * 32);
    floatx4 a00 = {0.f,0.f,0.f,0.f}, a10 = {0.f,0.f,0.f,0.f};
#pragma unroll
    for (int ks = 0; ks < 4; ++ks) {
      a00 = MFMA16(qf[0][ks], kf[ks], a00);
      a10 = MFMA16(qf[1][ks], kf[ks], a10);
    }
    float* o0 = orow + (size_t)(lg * 4) * 2048 + kt * 16 + lr;
    float* o1 = o0 + (size_t)16 * 2048;
#pragma unroll
    for (int j = 0; j < 4; ++j) {
      o0[(size_t)j * 2048] = __expf(a00[j]) * inv0[j];
      o1[(size_t)j * 2048] = __expf(a10[j]) * inv1[j];
    }
  }
}

// ----------------------------------------------------------------
extern "C" void kernel_launch(void* const* d_in, const int* in_sizes, int n_in,
                              void* d_out, int out_size, void* d_ws, size_t ws_size,
                              hipStream_t stream)
{
  const float* input = (const float*)d_in[0];
  const float* prev  = (const float*)d_in[1];
  const float* Wq = (const float*)d_in[2];
  const float* bq = (const float*)d_in[3];
  const float* Wk = (const float*)d_in[4];
  const float* bk = (const float*)d_in[5];
  const float* Wu = (const float*)d_in[8];
  const float* bu = (const float*)d_in[9];
  const float* Wr = (const float*)d_in[10];
  const float* br = (const float*)d_in[11];
  const float* Wc = (const float*)d_in[12];
  const float* bc = (const float*)d_in[13];

  float* out0 = (float*)d_out;                       // new_memory [8,2048,256]
  float* out1 = out0 + (size_t)8 * 2048 * 256;       // attention_probs [8,2048,2048]
  _Float16* ws = (_Float16*)d_ws;

  hipLaunchKernelGGL(k0_convert, dim3(1792), dim3(256), 0, stream, Wq, Wk, Wu, Wr, Wc, ws);
  hipLaunchKernelGGL(k1_proj,    dim3(64, 2, 2), dim3(256), 0, stream, input, prev, bq, bk, ws);

  if (ws_size >= (size_t)(OFF_T + 16384 * 256) * 2) {
    _Float16* tbuf = ws + OFF_T;
    hipLaunchKernelGGL(k2a_reset,  dim3(64, 4), dim3(256), 0, stream, input, prev, br, ws, tbuf);
    hipLaunchKernelGGL(k2b_update, dim3(64, 4), dim3(256), 0, stream, input, prev, bu, bc, ws, tbuf, out0);
  } else {
    hipLaunchKernelGGL(k2_fallback, dim3(512), dim3(256), 0, stream, input, prev, bu, br, bc, ws, out0);
  }

  hipLaunchKernelGGL(k3_attn, dim3(64, 8), dim3(512), 0, stream, ws, out1);
}

// Round 5
// 148.582 us; speedup vs baseline: 1.4613x; 1.1454x over previous
//
#include <hip/hip_runtime.h>

// DynamicMemoryCell: B=8, N=2048, IN=256, MEM=256, CTX=128
// out0 = new_memory [8,2048,256] f32 ; out1 = attention_probs [8,2048,2048] f32
// Wv/value/context dead in reference -> skipped.
//
// R4 structure: one weight-matrix per kernel (64 VGPR weight frags), activations
// streamed through 32 KB double-buffered LDS in 16-row chunks, 256-thr blocks.
// t = sigma(r)*m and u = sigma(u) intermediates live in the out1 region (k3
// overwrites it afterwards, stream-ordered). k3 = single MFMA pass, fp16
// numerators exp(s-14) held in registers, batch->XCD swizzled grid.

typedef _Float16 half8 __attribute__((ext_vector_type(8)));
typedef _Float16 half4 __attribute__((ext_vector_type(4)));
typedef float floatx4 __attribute__((ext_vector_type(4)));

#define MFMA16(a, b, c) __builtin_amdgcn_mfma_f32_16x16x32_f16((a), (b), (c), 0, 0, 0)

// ws layout (units: _Float16)
#define OFF_WQH 0
#define OFF_WQL 32768
#define OFF_WKH 65536
#define OFF_WKL 98304
#define OFF_WUH 131072
#define OFF_WRH 262144
#define OFF_WCH 393216
#define OFF_Q   524288
#define OFF_K   2621440
// total 4718592 halves = 9,437,184 bytes

// ---------------------------------------------------------------- K0: weights fp32 -> fp16 (hi/lo for Wq/Wk)
__global__ __launch_bounds__(256) void k0_convert(
    const float* __restrict__ Wq, const float* __restrict__ Wk,
    const float* __restrict__ Wu, const float* __restrict__ Wr,
    const float* __restrict__ Wc, _Float16* __restrict__ ws)
{
  int i = blockIdx.x * 256 + threadIdx.x;
  if (i < 32768) {
    float w = Wq[i];
    _Float16 h = (_Float16)w;
    ws[OFF_WQH + i] = h;
    ws[OFF_WQL + i] = (_Float16)(w - (float)h);
  } else if (i < 65536) {
    int j = i - 32768;
    float w = Wk[j];
    _Float16 h = (_Float16)w;
    ws[OFF_WKH + j] = h;
    ws[OFF_WKL + j] = (_Float16)(w - (float)h);
  } else {
    int j = i - 65536;
    if (j < 131072)      ws[OFF_WUH + j]            = (_Float16)Wu[j];
    else if (j < 262144) ws[OFF_WRH + (j - 131072)] = (_Float16)Wr[j - 131072];
    else                 ws[OFF_WCH + (j - 262144)] = (_Float16)Wc[j - 262144];
  }
}

// ---------------------------------------------------------------- K1: Q/K projection (split-fp16, 3 products)
// grid (64, 2, 2) x 256. x: 256-row block, y: 64-col half, z: 0=Q(input,Wq) 1=K(prev,Wk).
// Wave -> 16 cols; B hi/lo in 64 VGPR. A hi/lo staged in 16-row chunks (2x16 KB LDS).
__global__ __launch_bounds__(256) void k1_proj(
    const float* __restrict__ input, const float* __restrict__ prev,
    const float* __restrict__ bq, const float* __restrict__ bk,
    _Float16* __restrict__ ws)
{
  __shared__ char smem[2 * 16384];   // 16 rows x [hi 512B | lo 512B]
  const int which = blockIdx.z;
  const float* x = which ? prev : input;
  const _Float16* WH = ws + (which ? OFF_WKH : OFF_WQH);
  const _Float16* WL = ws + (which ? OFF_WKL : OFF_WQL);
  const float* bias = which ? bk : bq;
  _Float16* out = ws + (which ? OFF_K : OFF_Q);

  const int tid = threadIdx.x, w = tid >> 6, l = tid & 63;
  const int lr = l & 15, lg = l >> 4;
  const int rows0 = blockIdx.x * 256;
  const int c = blockIdx.y * 64 + w * 16 + lr;

  half8 bh[8], blw[8];
#pragma unroll
  for (int ks = 0; ks < 8; ++ks) {
    bh[ks]  = *(const half8*)(WH + (size_t)c * 256 + ks * 32 + lg * 8);
    blw[ks] = *(const half8*)(WL + (size_t)c * 256 + ks * 32 + lg * 8);
  }
  const float bv = bias[c];
  floatx4 st[4];

#define K1_LOAD(ch) { const float* src = x + ((size_t)rows0 + (ch) * 16) * 256 + tid * 4; \
  _Pragma("unroll") for (int r = 0; r < 4; ++r) st[r] = *(const floatx4*)(src + r * 1024); }
#define K1_WRITE(ch) { char* bufw = smem + ((ch) & 1) * 16384; \
  _Pragma("unroll") for (int r = 0; r < 4; ++r) { \
    int e = r * 1024 + tid * 4, row = e >> 8, col = e & 255; \
    half4 h, lo; \
    _Pragma("unroll") for (int j = 0; j < 4; ++j) { \
      float f = st[r][j]; h[j] = (_Float16)f; lo[j] = (_Float16)(f - (float)h[j]); } \
    int o = row * 1024 + ((col * 2) ^ ((row & 7) << 4)); \
    *(half4*)(bufw + o) = h; *(half4*)(bufw + o + 512) = lo; } }

  K1_LOAD(0); K1_WRITE(0);
  __syncthreads();
#pragma unroll 1
  for (int ch = 0; ch < 16; ++ch) {
    if (ch < 15) K1_LOAD(ch + 1);
    const char* buf = smem + (ch & 1) * 16384;
    floatx4 acc = {0.f, 0.f, 0.f, 0.f};
    const int base = lr * 1024, sz = (lr & 7) << 4;
#pragma unroll
    for (int ks = 0; ks < 8; ++ks) {
      int o = base + ((ks * 64 + lg * 16) ^ sz);
      half8 ah = *(const half8*)(buf + o);
      half8 al = *(const half8*)(buf + o + 512);
      acc = MFMA16(ah, bh[ks], acc);
      acc = MFMA16(al, bh[ks], acc);
      acc = MFMA16(ah, blw[ks], acc);
    }
#pragma unroll
    for (int j = 0; j < 4; ++j)
      out[((size_t)rows0 + ch * 16 + lg * 4 + j) * 128 + c] = (_Float16)(acc[j] + bv);
    if (ch < 15) K1_WRITE(ch + 1);
    __syncthreads();
  }
}

// ---------------------------------------------------------------- K2ru: reset (z=0 -> t) / update (z=1 -> u)
// grid (64, 4, 2) x 256. Wave -> 16 cols, one matrix slice = 64 VGPR.
// A = [input|prev] fp16, 16-row chunks (2x16 KB LDS).
__global__ __launch_bounds__(256) void k2ru(
    const float* __restrict__ input, const float* __restrict__ prev,
    const float* __restrict__ br, const float* __restrict__ bu,
    const _Float16* __restrict__ ws,
    _Float16* __restrict__ t_sc, _Float16* __restrict__ u_sc)
{
  __shared__ char smem[2 * 16384];   // 16 rows x [in 512B | prev 512B]
  const int z = blockIdx.z;
  const int tid = threadIdx.x, w = tid >> 6, l = tid & 63;
  const int lr = l & 15, lg = l >> 4;
  const int rows0 = blockIdx.x * 256;
  const int c = blockIdx.y * 64 + w * 16 + lr;

  const _Float16* W = ws + (z ? OFF_WUH : OFF_WRH);
  half8 bw[16];
#pragma unroll
  for (int ks = 0; ks < 16; ++ks)
    bw[ks] = *(const half8*)(W + (size_t)c * 512 + ks * 32 + lg * 8);
  const float bv = (z ? bu : br)[c];
  floatx4 stI[4], stP[4];

#define K2RU_LOAD(ch) { \
  const float* si = input + ((size_t)rows0 + (ch) * 16) * 256 + tid * 4; \
  const float* sp = prev  + ((size_t)rows0 + (ch) * 16) * 256 + tid * 4; \
  _Pragma("unroll") for (int r = 0; r < 4; ++r) { stI[r] = *(const floatx4*)(si + r * 1024); \
                                                  stP[r] = *(const floatx4*)(sp + r * 1024); } }
#define K2RU_WRITE(ch) { char* bufw = smem + ((ch) & 1) * 16384; \
  _Pragma("unroll") for (int r = 0; r < 4; ++r) { \
    int e = r * 1024 + tid * 4, row = e >> 8, col = e & 255; \
    half4 h, hp; \
    _Pragma("unroll") for (int j = 0; j < 4; ++j) { h[j] = (_Float16)stI[r][j]; hp[j] = (_Float16)stP[r][j]; } \
    int o = row * 1024 + ((col * 2) ^ ((row & 7) << 4)); \
    *(half4*)(bufw + o) = h; *(half4*)(bufw + o + 512) = hp; } }

  K2RU_LOAD(0); K2RU_WRITE(0);
  __syncthreads();
#pragma unroll 1
  for (int ch = 0; ch < 16; ++ch) {
    if (ch < 15) K2RU_LOAD(ch + 1);
    const char* buf = smem + (ch & 1) * 16384;
    floatx4 acc = {0.f, 0.f, 0.f, 0.f};
    const int base = lr * 1024, sz = (lr & 7) << 4;
#pragma unroll
    for (int ks = 0; ks < 16; ++ks) {   // ks>=8 lands in [512,1024) = prev half
      int o = base + ((ks * 64 + lg * 16) ^ sz);
      half8 a = *(const half8*)(buf + o);
      acc = MFMA16(a, bw[ks], acc);
    }
#pragma unroll
    for (int j = 0; j < 4; ++j) {
      const int crow = lg * 4 + j;
      const size_t grow = (size_t)rows0 + ch * 16 + crow;
      float g = 1.f / (1.f + __expf(-(acc[j] + bv)));
      if (z == 0) {
        int moff = crow * 1024 + ((c * 2) ^ ((crow & 7) << 4)) + 512;
        float m = (float)*(const _Float16*)(buf + moff);
        t_sc[grow * 256 + c] = (_Float16)(g * m);
      } else {
        u_sc[grow * 256 + c] = (_Float16)g;
      }
    }
    if (ch < 15) K2RU_WRITE(ch + 1);
    __syncthreads();
  }
}

// ---------------------------------------------------------------- K2c: candidate + combine -> out0
// grid (64, 4) x 256. A = [input | t], Wc slice 64 VGPR; epilogue reads u (fp16) + m (f32).
__global__ __launch_bounds__(256) void k2c(
    const float* __restrict__ input, const float* __restrict__ prev,
    const float* __restrict__ bc, const _Float16* __restrict__ ws,
    const _Float16* __restrict__ t_sc, const _Float16* __restrict__ u_sc,
    float* __restrict__ out0)
{
  __shared__ char smem[2 * 16384];   // 16 rows x [in 512B | t 512B]
  const int tid = threadIdx.x, w = tid >> 6, l = tid & 63;
  const int lr = l & 15, lg = l >> 4;
  const int rows0 = blockIdx.x * 256;
  const int c = blockIdx.y * 64 + w * 16 + lr;

  half8 bw[16];
#pragma unroll
  for (int ks = 0; ks < 16; ++ks)
    bw[ks] = *(const half8*)(ws + OFF_WCH + (size_t)c * 512 + ks * 32 + lg * 8);
  const float bv = bc[c];
  floatx4 stI[4];
  half4 stT[4];

#define K2C_LOAD(ch) { \
  const float* si = input + ((size_t)rows0 + (ch) * 16) * 256 + tid * 4; \
  const _Float16* stp = t_sc + ((size_t)rows0 + (ch) * 16) * 256 + tid * 4; \
  _Pragma("unroll") for (int r = 0; r < 4; ++r) { stI[r] = *(const floatx4*)(si + r * 1024); \
                                                  stT[r] = *(const half4*)(stp + r * 1024); } }
#define K2C_WRITE(ch) { char* bufw = smem + ((ch) & 1) * 16384; \
  _Pragma("unroll") for (int r = 0; r < 4; ++r) { \
    int e = r * 1024 + tid * 4, row = e >> 8, col = e & 255; \
    half4 h; \
    _Pragma("unroll") for (int j = 0; j < 4; ++j) h[j] = (_Float16)stI[r][j]; \
    int o = row * 1024 + ((col * 2) ^ ((row & 7) << 4)); \
    *(half4*)(bufw + o) = h; *(half4*)(bufw + o + 512) = stT[r]; } }

  K2C_LOAD(0); K2C_WRITE(0);
  __syncthreads();
#pragma unroll 1
  for (int ch = 0; ch < 16; ++ch) {
    if (ch < 15) K2C_LOAD(ch + 1);
    const char* buf = smem + (ch & 1) * 16384;
    floatx4 acc = {0.f, 0.f, 0.f, 0.f};
    const int base = lr * 1024, sz = (lr & 7) << 4;
#pragma unroll
    for (int ks = 0; ks < 16; ++ks) {   // ks>=8 = t half
      int o = base + ((ks * 64 + lg * 16) ^ sz);
      half8 a = *(const half8*)(buf + o);
      acc = MFMA16(a, bw[ks], acc);
    }
#pragma unroll
    for (int j = 0; j < 4; ++j) {
      const size_t grow = (size_t)rows0 + ch * 16 + lg * 4 + j;
      float e2 = __expf(2.f * (acc[j] + bv));
      float cg = (e2 - 1.f) / (e2 + 1.f);
      float u = (float)u_sc[grow * 256 + c];
      float m = prev[grow * 256 + c];
      out0[grow * 256 + c] = (1.f - u) * m + u * cg;
    }
    if (ch < 15) K2C_WRITE(ch + 1);
    __syncthreads();
  }
}

// ---------------------------------------------------------------- K3: attention, single MFMA pass
// grid (8, 64) x 256: blockIdx.x = batch -> XCD (bid%8=batch, K slice L2-resident).
// Block = 32 q-rows; 4 waves x 512 keys. Numerators exp(s-14) held fp16 in regs.
__global__ __launch_bounds__(256) void k3_attn(
    const _Float16* __restrict__ ws, float* __restrict__ out1)
{
  __shared__ float sums[4][32];
  const int b = blockIdx.x;
  const int q0 = blockIdx.y * 32;
  const int tid = threadIdx.x, w = tid >> 6, l = tid & 63;
  const int lr = l & 15, lg = l >> 4;

  const _Float16* Q  = ws + OFF_Q + ((size_t)b * 2048 + q0) * 128;
  const _Float16* Kp = ws + OFF_K + (size_t)b * 2048 * 128 + (size_t)w * 512 * 128;

  half8 qf[2][4];
#pragma unroll
  for (int qt = 0; qt < 2; ++qt)
#pragma unroll
    for (int ks = 0; ks < 4; ++ks)
      qf[qt][ks] = *(const half8*)(Q + (size_t)(qt * 16 + lr) * 128 + ks * 32 + lg * 8);

  half4 ex0[32], ex1[32];
  float se0[4] = {0.f,0.f,0.f,0.f}, se1[4] = {0.f,0.f,0.f,0.f};
#pragma unroll
  for (int kt = 0; kt < 32; ++kt) {
    const _Float16* kp = Kp + (size_t)(kt * 16 + lr) * 128 + lg * 8;
    half8 kf[4];
#pragma unroll
    for (int ks = 0; ks < 4; ++ks) kf[ks] = *(const half8*)(kp + ks * 32);
    floatx4 a0 = {0.f,0.f,0.f,0.f}, a1 = {0.f,0.f,0.f,0.f};
#pragma unroll
    for (int ks = 0; ks < 4; ++ks) {
      a0 = MFMA16(qf[0][ks], kf[ks], a0);
      a1 = MFMA16(qf[1][ks], kf[ks], a1);
    }
    half4 e0, e1;
#pragma unroll
    for (int j = 0; j < 4; ++j) {
      float f0 = __expf(a0[j] - 14.f); se0[j] += f0; e0[j] = (_Float16)f0;
      float f1 = __expf(a1[j] - 14.f); se1[j] += f1; e1[j] = (_Float16)f1;
    }
    ex0[kt] = e0; ex1[kt] = e1;
  }
#pragma unroll
  for (int m = 1; m < 16; m <<= 1) {
#pragma unroll
    for (int j = 0; j < 4; ++j) { se0[j] += __shfl_xor(se0[j], m); se1[j] += __shfl_xor(se1[j], m); }
  }
  if (lr == 0) {
#pragma unroll
    for (int j = 0; j < 4; ++j) { sums[w][lg * 4 + j] = se0[j]; sums[w][16 + lg * 4 + j] = se1[j]; }
  }
  __syncthreads();
  float inv0[4], inv1[4];
#pragma unroll
  for (int j = 0; j < 4; ++j) {
    int r0 = lg * 4 + j, r1 = 16 + lg * 4 + j;
    inv0[j] = 1.f / (sums[0][r0] + sums[1][r0] + sums[2][r0] + sums[3][r0]);
    inv1[j] = 1.f / (sums[0][r1] + sums[1][r1] + sums[2][r1] + sums[3][r1]);
  }

  float* orow = out1 + ((size_t)b * 2048 + q0) * 2048 + w * 512;
#pragma unroll
  for (int kt = 0; kt < 32; ++kt) {
    float* o0 = orow + (size_t)(lg * 4) * 2048 + kt * 16 + lr;
    float* o1 = o0 + (size_t)16 * 2048;
#pragma unroll
    for (int j = 0; j < 4; ++j) {
      o0[(size_t)j * 2048] = (float)ex0[kt][j] * inv0[j];
      o1[(size_t)j * 2048] = (float)ex1[kt][j] * inv1[j];
    }
  }
}

// ----------------------------------------------------------------
extern "C" void kernel_launch(void* const* d_in, const int* in_sizes, int n_in,
                              void* d_out, int out_size, void* d_ws, size_t ws_size,
                              hipStream_t stream)
{
  const float* input = (const float*)d_in[0];
  const float* prev  = (const float*)d_in[1];
  const float* Wq = (const float*)d_in[2];
  const float* bq = (const float*)d_in[3];
  const float* Wk = (const float*)d_in[4];
  const float* bk = (const float*)d_in[5];
  const float* Wu = (const float*)d_in[8];
  const float* bu = (const float*)d_in[9];
  const float* Wr = (const float*)d_in[10];
  const float* br = (const float*)d_in[11];
  const float* Wc = (const float*)d_in[12];
  const float* bc = (const float*)d_in[13];

  float* out0 = (float*)d_out;                        // new_memory [8,2048,256]
  float* out1 = out0 + (size_t)8 * 2048 * 256;        // attention_probs [8,2048,2048]
  _Float16* ws = (_Float16*)d_ws;                     // 9,437,184 bytes used

  // t/u intermediates live in the out1 region (k3 overwrites it afterwards)
  _Float16* t_sc = (_Float16*)out1;                   // 4.19M halves
  _Float16* u_sc = (_Float16*)out1 + 4194304;         // 4.19M halves

  hipLaunchKernelGGL(k0_convert, dim3(1792), dim3(256), 0, stream, Wq, Wk, Wu, Wr, Wc, ws);
  hipLaunchKernelGGL(k1_proj,    dim3(64, 2, 2), dim3(256), 0, stream, input, prev, bq, bk, ws);
  hipLaunchKernelGGL(k2ru,       dim3(64, 4, 2), dim3(256), 0, stream, input, prev, br, bu, ws, t_sc, u_sc);
  hipLaunchKernelGGL(k2c,        dim3(64, 4), dim3(256), 0, stream, input, prev, bc, ws, t_sc, u_sc, out0);
  hipLaunchKernelGGL(k3_attn,    dim3(8, 64), dim3(256), 0, stream, ws, out1);
}